// Round 7
// baseline (118.064 us; speedup 1.0000x reference)
//
#include <hip/hip_runtime.h>
#include <stdint.h>

// Problem shape (fixed by reference setup_inputs): B=4096, L=2048.
#define LROW 2048
#define THREADS 256
#define NBINS 2048

// One block per row. Stable argsort of (masked -> +inf) keys; only the first
// `valid` outputs are observable, so masked elements are DROPPED. Valid
// elements are bucket-scattered by value (uniform [0,1) -> ~0.5/bin over 2048
// bins; bucket fn floor(t*2048) clamped is MONOTONE in key order, so the
// array is sorted across buckets by construction), then each bucket is
// insertion-sorted on the full composite key (sortable_bits<<32)|idx --
// all-distinct keys, ties in t break by lower index == stable argsort ==
// the reference's greedy argmin semantics.
//
// NOTE: mask (jnp.bool_) is uploaded by the harness as int32 ("integer ->
// const int*"), one element per int. Round-3 failure (absmax==2048 ==
// pad-vs-index mismatch -> wrong valid count) was the uchar4 misread.
__global__ __launch_bounds__(THREADS) void time_greedy_bucket_kernel(
    const float* __restrict__ time,
    const int* __restrict__ mask,             // int32: nonzero = excluded
    const int* __restrict__ pad_value_p,
    int* __restrict__ pred,                   // [B, L] int32
    int* __restrict__ valid_out)              // [B]    int32
{
    __shared__ uint64_t keys[LROW];      // 16 KB: scattered composite keys
    __shared__ uint32_t hist[NBINS];     // 8 KB: counts -> running positions -> ends
    __shared__ uint32_t wsum[4];         // per-wave scan totals

    const int row = blockIdx.x;
    const int tid = threadIdx.x;
    const int lane = tid & 63;
    const int wid = tid >> 6;

    // ---- init LDS ----
#pragma unroll
    for (int e = 0; e < NBINS / THREADS; ++e) {
        hist[tid + e * THREADS] = 0;
        keys[tid + e * THREADS] = ~0ull;   // sentinel (never emitted; pad covers)
    }
    __syncthreads();

    // ---- vectorized load + histogram of valid elements ----
    const float4* trow4 = (const float4*)(time + (size_t)row * LROW);
    const int4*   mrow4 = (const int4*)(mask + (size_t)row * LROW);

    uint32_t ukey[8];
    int      bkt[8];
    int      mval[8];
#pragma unroll
    for (int c = 0; c < 2; ++c) {
        const int v = tid + c * THREADS;
        const float4 tq = trow4[v];
        const int4   mq = mrow4[v];
        const float tf[4] = {tq.x, tq.y, tq.z, tq.w};
        const int   mf[4] = {mq.x, mq.y, mq.z, mq.w};
#pragma unroll
        for (int j = 0; j < 4; ++j) {
            const int e = c * 4 + j;
            const uint32_t fb = __float_as_uint(tf[j]);
            // order-preserving float->uint transform (general form)
            ukey[e] = fb ^ ((uint32_t)((int32_t)fb >> 31) | 0x80000000u);
            int b = (int)(tf[j] * (float)NBINS);   // monotone value bucketing
            b = (b < 0) ? 0 : ((b > NBINS - 1) ? NBINS - 1 : b);
            bkt[e] = b;
            mval[e] = mf[j];
            if (!mf[j]) atomicAdd(&hist[b], 1u);
        }
    }
    __syncthreads();

    // ---- exclusive prefix sum over 2048 bins (wave-shuffle scan, 1 barrier) ----
    uint32_t h[8];
    uint32_t lsum = 0;
#pragma unroll
    for (int e = 0; e < 8; ++e) {
        h[e] = hist[tid * 8 + e];
        lsum += h[e];
    }
    // inclusive scan of lsum within the 64-lane wave
    uint32_t incl = lsum;
#pragma unroll
    for (int off = 1; off < 64; off <<= 1) {
        const uint32_t y = __shfl_up(incl, off, 64);
        if (lane >= off) incl += y;
    }
    if (lane == 63) wsum[wid] = incl;
    __syncthreads();
    uint32_t woff = 0, total = 0;
#pragma unroll
    for (int w = 0; w < 4; ++w) {
        const uint32_t s = wsum[w];
        if (w < wid) woff += s;
        total += s;
    }
    uint32_t run = woff + incl - lsum;   // exclusive prefix for this thread's bins
#pragma unroll
    for (int e = 0; e < 8; ++e) {
        hist[tid * 8 + e] = run;         // exclusive bin start (running position)
        run += h[e];
    }
    __syncthreads();

    // ---- scatter valid elements into their bucket ranges ----
#pragma unroll
    for (int c = 0; c < 2; ++c) {
#pragma unroll
        for (int j = 0; j < 4; ++j) {
            const int e = c * 4 + j;
            if (!mval[e]) {
                const int i = 4 * tid + c * (4 * THREADS) + j;  // element index
                const uint32_t pos = atomicAdd(&hist[bkt[e]], 1u);
                keys[pos] = ((uint64_t)ukey[e] << 32) | (uint32_t)i;
            }
        }
    }
    __syncthreads();
    // Post-scatter invariant: hist[b] == inclusive end of bucket b;
    // bucket b start == (b==0) ? 0 : hist[b-1]. Cross-bucket order correct.

    // ---- per-bucket insertion sort (disjoint ranges, no barriers) ----
#pragma unroll
    for (int q = 0; q < NBINS / THREADS; ++q) {
        const int b = tid * (NBINS / THREADS) + q;
        const uint32_t start = (b == 0) ? 0u : hist[b - 1];
        const uint32_t end = hist[b];
        for (uint32_t i = start + 1; i < end; ++i) {
            const uint64_t v = keys[i];
            uint32_t j = i;
            while (j > start && keys[j - 1] > v) {
                keys[j] = keys[j - 1];
                --j;
            }
            keys[j] = v;
        }
    }
    __syncthreads();

    // ---- emit: first `total` sorted indices, pad_value afterwards ----
    const int vld = (int)total;
    const int pad = pad_value_p[0];
    int4* prow4 = (int4*)(pred + (size_t)row * LROW);
#pragma unroll
    for (int c = 0; c < 2; ++c) {
        const int v = tid + c * THREADS;
        const int base = 4 * v;
        int4 o;
        o.x = (base + 0 < vld) ? (int)(uint32_t)keys[base + 0] : pad;
        o.y = (base + 1 < vld) ? (int)(uint32_t)keys[base + 1] : pad;
        o.z = (base + 2 < vld) ? (int)(uint32_t)keys[base + 2] : pad;
        o.w = (base + 3 < vld) ? (int)(uint32_t)keys[base + 3] : pad;
        prow4[v] = o;
    }
    if (tid == 0) valid_out[row] = vld;
}

extern "C" void kernel_launch(void* const* d_in, const int* in_sizes, int n_in,
                              void* d_out, int out_size, void* d_ws, size_t ws_size,
                              hipStream_t stream) {
    const float* time = (const float*)d_in[0];
    const int* mask = (const int*)d_in[1];
    const int* pad_value = (const int*)d_in[2];

    const int B = in_sizes[0] / LROW;

    // d_out layout: pred [B*L] int32, then valid [B] int32 (tuple concat order)
    int* pred = (int*)d_out;
    int* valid_out = pred + (size_t)B * LROW;

    time_greedy_bucket_kernel<<<B, THREADS, 0, stream>>>(time, mask, pad_value,
                                                         pred, valid_out);
}

// Round 8
// 113.713 us; speedup vs baseline: 1.0383x; 1.0383x over previous
//
#include <hip/hip_runtime.h>
#include <stdint.h>

// Problem shape (fixed by reference setup_inputs): B=4096, L=2048.
#define LROW 2048
#define THREADS 256
#define NBINS 1024
#define BPT (NBINS / THREADS)   // 4 bins owned per thread (contiguous bin ids)

// hist is stored TRANSPOSED so that thread-contiguous bin ownership maps to
// lane-stride-1 LDS access: bin b lives at hist[(b&3)*256 + (b>>2)].
// Round-7 profile showed 4.7M bank-conflict cycles, mostly from u32-stride-8
// (16-way) hist access in scan/insertion and u64-stride-4 emit reads.
__device__ __forceinline__ int swz(int b) {
    return ((b & (BPT - 1)) << 8) + (b >> 2);
}

// One block per row. Stable argsort of (masked -> +inf) keys; masked elements
// are DROPPED (outputs past `valid` are pad). Valid elements bucket-scatter
// by value (monotone fn floor(t*1024) -> cross-bucket order by construction),
// then per-bucket insertion sort on composite key (sortable_bits<<32)|idx
// (all-distinct; ties in t break by lower index == stable argsort == the
// reference's greedy argmin semantics).
//
// mask (jnp.bool_) is uploaded by the harness as int32.
__global__ __launch_bounds__(THREADS) void time_greedy_bucket_kernel(
    const float* __restrict__ time,
    const int* __restrict__ mask,             // int32: nonzero = excluded
    const int* __restrict__ pad_value_p,
    int* __restrict__ pred,                   // [B, L] int32
    int* __restrict__ valid_out)              // [B]    int32
{
    __shared__ uint64_t keys[LROW];      // 16 KB; NO init needed: scatter fills
                                         // exactly [0, valid) and emit never
                                         // consumes past vld (pad branch).
    __shared__ uint32_t hist[NBINS];     // 4 KB, transposed layout via swz()
    __shared__ uint32_t wsum[4];         // per-wave scan totals

    const int row = blockIdx.x;
    const int tid = threadIdx.x;
    const int lane = tid & 63;
    const int wid = tid >> 6;

    // ---- init hist (stride-1, conflict-free) ----
#pragma unroll
    for (int e = 0; e < BPT; ++e) hist[tid + e * THREADS] = 0;
    __syncthreads();

    // ---- vectorized load + histogram of valid elements ----
    const float4* trow4 = (const float4*)(time + (size_t)row * LROW);
    const int4*   mrow4 = (const int4*)(mask + (size_t)row * LROW);

    uint32_t ukey[8];
    int      bkt[8];
    int      mval[8];
#pragma unroll
    for (int c = 0; c < 2; ++c) {
        const int v = tid + c * THREADS;
        const float4 tq = trow4[v];
        const int4   mq = mrow4[v];
        const float tf[4] = {tq.x, tq.y, tq.z, tq.w};
        const int   mf[4] = {mq.x, mq.y, mq.z, mq.w};
#pragma unroll
        for (int j = 0; j < 4; ++j) {
            const int e = c * 4 + j;
            const uint32_t fb = __float_as_uint(tf[j]);
            // order-preserving float->uint transform (general form)
            ukey[e] = fb ^ ((uint32_t)((int32_t)fb >> 31) | 0x80000000u);
            int b = (int)(tf[j] * (float)NBINS);   // monotone value bucketing
            b = (b < 0) ? 0 : ((b > NBINS - 1) ? NBINS - 1 : b);
            bkt[e] = b;
            mval[e] = mf[j];
            if (!mf[j]) atomicAdd(&hist[swz(b)], 1u);   // random bins
        }
    }
    __syncthreads();

    // ---- exclusive prefix sum over 1024 bins ----
    // Thread t owns bins 4t..4t+3; transposed layout -> stride-1 lane access.
    uint32_t h[BPT];
    uint32_t lsum = 0;
#pragma unroll
    for (int e = 0; e < BPT; ++e) {
        h[e] = hist[e * THREADS + tid];
        lsum += h[e];
    }
    // inclusive scan of lsum within the 64-lane wave
    uint32_t incl = lsum;
#pragma unroll
    for (int off = 1; off < 64; off <<= 1) {
        const uint32_t y = __shfl_up(incl, off, 64);
        if (lane >= off) incl += y;
    }
    if (lane == 63) wsum[wid] = incl;
    __syncthreads();
    uint32_t woff = 0, total = 0;
#pragma unroll
    for (int w = 0; w < 4; ++w) {
        const uint32_t s = wsum[w];
        if (w < wid) woff += s;
        total += s;
    }
    uint32_t run = woff + incl - lsum;   // exclusive prefix for this thread's bins
#pragma unroll
    for (int e = 0; e < BPT; ++e) {
        hist[e * THREADS + tid] = run;   // exclusive bin start (running position)
        run += h[e];
    }
    __syncthreads();

    // ---- scatter valid elements into their bucket ranges ----
#pragma unroll
    for (int c = 0; c < 2; ++c) {
#pragma unroll
        for (int j = 0; j < 4; ++j) {
            const int e = c * 4 + j;
            if (!mval[e]) {
                const int i = 4 * tid + c * (4 * THREADS) + j;  // element index
                const uint32_t pos = atomicAdd(&hist[swz(bkt[e])], 1u);
                keys[pos] = ((uint64_t)ukey[e] << 32) | (uint32_t)i;
            }
        }
    }
    __syncthreads();
    // Post-scatter invariant: hist[swz(b)] == inclusive end of bucket b;
    // bucket b start == (b==0) ? 0 : hist[swz(b-1)]. Cross-bucket order holds.

    // ---- per-bucket insertion sort (disjoint ranges, no barriers) ----
    // Range reads are stride-1 across lanes thanks to the transposed hist.
#pragma unroll
    for (int e = 0; e < BPT; ++e) {
        const int b = BPT * tid + e;
        const uint32_t start = (b == 0) ? 0u : hist[swz(b - 1)];
        const uint32_t end = hist[swz(b)];
        for (uint32_t i = start + 1; i < end; ++i) {
            const uint64_t v = keys[i];
            uint32_t j = i;
            while (j > start && keys[j - 1] > v) {
                keys[j] = keys[j - 1];
                --j;
            }
            keys[j] = v;
        }
    }
    __syncthreads();

    // ---- emit: stride-1 LDS reads + scalar coalesced global writes ----
    const int vld = (int)total;
    const int pad = pad_value_p[0];
    int* prow = pred + (size_t)row * LROW;
#pragma unroll
    for (int c = 0; c < LROW / THREADS; ++c) {
        const int i = tid + c * THREADS;
        const uint64_t k = keys[i];          // stride-1 u64: conflict-free
        prow[i] = (i < vld) ? (int)(uint32_t)k : pad;  // 256B/wave coalesced
    }
    if (tid == 0) valid_out[row] = vld;
}

extern "C" void kernel_launch(void* const* d_in, const int* in_sizes, int n_in,
                              void* d_out, int out_size, void* d_ws, size_t ws_size,
                              hipStream_t stream) {
    const float* time = (const float*)d_in[0];
    const int* mask = (const int*)d_in[1];
    const int* pad_value = (const int*)d_in[2];

    const int B = in_sizes[0] / LROW;

    // d_out layout: pred [B*L] int32, then valid [B] int32 (tuple concat order)
    int* pred = (int*)d_out;
    int* valid_out = pred + (size_t)B * LROW;

    time_greedy_bucket_kernel<<<B, THREADS, 0, stream>>>(time, mask, pad_value,
                                                         pred, valid_out);
}